// Round 1
// baseline (179.694 us; speedup 1.0000x reference)
//
#include <hip/hip_runtime.h>

#define DD 768
#define NCH 96
#define NTOK 32   // tokens per wave-chunk in main kernel

__device__ __forceinline__ float wave_reduce_sum(float v) {
#pragma unroll
  for (int m = 32; m >= 1; m >>= 1) v += __shfl_xor(v, m, 64);
  return v;
}

// ---------- histogram of labels (LDS-aggregated) ----------
__global__ void k_hist(const int* __restrict__ tgt, int n, int* __restrict__ hist) {
  __shared__ int lh[NCH];
  int tid = threadIdx.x;
  if (tid < NCH) lh[tid] = 0;
  __syncthreads();
  for (int i = blockIdx.x * blockDim.x + tid; i < n; i += gridDim.x * blockDim.x)
    atomicAdd(&lh[tgt[i]], 1);
  __syncthreads();
  if (tid < NCH) atomicAdd(&hist[tid], lh[tid]);
}

// ---------- exclusive scan of 96 counts (trivial) ----------
__global__ void k_scan(const int* __restrict__ hist, int* __restrict__ offs) {
  if (threadIdx.x == 0) {
    int r = 0;
    for (int c = 0; c < NCH; ++c) { offs[c] = r; r += hist[c]; }
  }
}

// ---------- counting-sort token indices by label (block-aggregated) ----------
__global__ void k_scatter(const int* __restrict__ tgt, int n,
                          const int* __restrict__ offs, int* __restrict__ cursor,
                          int* __restrict__ sorted) {
  __shared__ int lcnt[NCH];
  __shared__ int lbase[NCH];
  int tid = threadIdx.x;
  int i = blockIdx.x * blockDim.x + tid;
  if (tid < NCH) lcnt[tid] = 0;
  __syncthreads();
  int c = -1, r = 0;
  if (i < n) { c = tgt[i]; r = atomicAdd(&lcnt[c], 1); }
  __syncthreads();
  if (tid < NCH && lcnt[tid] > 0) lbase[tid] = atomicAdd(&cursor[tid], lcnt[tid]);
  __syncthreads();
  if (i < n) sorted[offs[c] + lbase[c] + r] = i;
}

// ---------- main: one read of input_f; fused LN-stats + per-label register accumulation ----------
__global__ void __launch_bounds__(256) k_main(
    const float* __restrict__ x, const int* __restrict__ sorted,
    const int* __restrict__ offs, const int* __restrict__ hist,
    float* __restrict__ S1, float* __restrict__ Mc, int virtWaves) {
  int lane = threadIdx.x & 63;
  int gw = (blockIdx.x * blockDim.x + threadIdx.x) >> 6;
  int totalWaves = (gridDim.x * blockDim.x) >> 6;

  for (int p = gw; p < virtWaves; p += totalWaves) {
    int c = p % NCH;          // label
    int j = p / NCH;          // chunk within label
    int n = hist[c];
    int beg = j * NTOK;
    if (beg >= n) continue;
    int end = min(beg + NTOK, n);
    const int* lst = sorted + offs[c];

    float acc[12];
#pragma unroll
    for (int k = 0; k < 12; ++k) acc[k] = 0.f;
    float mcp = 0.f;

    for (int i = beg; i < end; ++i) {
      int t = lst[i];
      const float4* row = (const float4*)(x + (size_t)t * DD);
      float4 A = row[lane];
      float4 B = row[64 + lane];
      float4 C = row[128 + lane];
      float v[12] = {A.x, A.y, A.z, A.w, B.x, B.y, B.z, B.w, C.x, C.y, C.z, C.w};
      float s = 0.f, q = 0.f;
#pragma unroll
      for (int k = 0; k < 12; ++k) { s += v[k]; q += v[k] * v[k]; }
      s = wave_reduce_sum(s);
      q = wave_reduce_sum(q);
      float mu = s * (1.f / DD);
      float var = q * (1.f / DD) - mu * mu;
      float rstd = rsqrtf(var + 1e-5f);
#pragma unroll
      for (int k = 0; k < 12; ++k) acc[k] += rstd * v[k];
      mcp += rstd * mu;
    }

    float* S1r = S1 + c * DD;
#pragma unroll
    for (int k = 0; k < 12; ++k) {
      int d = (k >> 2) * 256 + 4 * lane + (k & 3);
      atomicAdd(&S1r[d], acc[k]);
    }
    if (lane == 0) atomicAdd(&Mc[c], mcp);
  }
}

// ---------- finish: 96x768 tail math -> scalar ----------
__global__ void __launch_bounds__(1024) k_finish(
    const float* __restrict__ dic, const float* __restrict__ w,
    const float* __restrict__ b, const float* __restrict__ S1,
    const float* __restrict__ Mc, const int* __restrict__ hist,
    float* __restrict__ out) {
  __shared__ float s_sh[DD];
  __shared__ float pos_sh;
  __shared__ float wred[16];
  int tid = threadIdx.x, lane = tid & 63, wv = tid >> 6;
  for (int i = tid; i < DD; i += 1024) s_sh[i] = 0.f;
  if (tid == 0) pos_sh = 0.f;
  __syncthreads();

  float sacc[12];
#pragma unroll
  for (int k = 0; k < 12; ++k) sacc[k] = 0.f;
  float pacc = 0.f;

  for (int c = wv; c < NCH; c += 16) {
    float nc = (float)hist[c];
    float mc = Mc[c];
    float gs[12];
#pragma unroll
    for (int k = 0; k < 12; ++k) {
      int d = (k >> 2) * 256 + 4 * lane + (k & 3);
      float g = dic[c * DD + d] + w[d] * (S1[c * DD + d] - mc) + nc * b[d];
      gs[k] = g;
      pacc += g * g;
    }
    if (c >= 1) {
      float inv = 1.f / (nc + 1.f);
      float nch[12];
      float sum = 0.f, sq = 0.f;
#pragma unroll
      for (int k = 0; k < 12; ++k) {
        int d = (k >> 2) * 256 + 4 * lane + (k & 3);
        float u = dic[c * DD + d] + 0.1f * gs[k] * inv;
        nch[k] = u;
        sum += u;
        sq += u * u;
      }
      sum = wave_reduce_sum(sum);
      sq = wave_reduce_sum(sq);
      float mu = sum * (1.f / DD);
      float rstd = rsqrtf(sq * (1.f / DD) - mu * mu + 1e-5f);
#pragma unroll
      for (int k = 0; k < 12; ++k) {
        int d = (k >> 2) * 256 + 4 * lane + (k & 3);
        sacc[k] += (nch[k] - mu) * rstd * w[d] + b[d];
      }
    }
  }

  pacc = wave_reduce_sum(pacc);
  if (lane == 0) atomicAdd(&pos_sh, pacc);
#pragma unroll
  for (int k = 0; k < 12; ++k) {
    int d = (k >> 2) * 256 + 4 * lane + (k & 3);
    atomicAdd(&s_sh[d], sacc[k]);
  }
  __syncthreads();

  float nv = (tid < DD) ? s_sh[tid] * s_sh[tid] : 0.f;
  nv = wave_reduce_sum(nv);
  if (lane == 0) wred[wv] = nv;
  __syncthreads();
  if (tid == 0) {
    float tot = 0.f;
    for (int i = 0; i < 16; ++i) tot += wred[i];
    out[0] = tot * (1.f / DD) - pos_sh * (1.f / DD);
  }
}

extern "C" void kernel_launch(void* const* d_in, const int* in_sizes, int n_in,
                              void* d_out, int out_size, void* d_ws, size_t ws_size,
                              hipStream_t stream) {
  (void)n_in; (void)out_size; (void)ws_size;
  const float* x   = (const float*)d_in[0];
  const float* dic = (const float*)d_in[1];
  const float* w   = (const float*)d_in[2];
  const float* b   = (const float*)d_in[3];
  const int*   tgt = (const int*)d_in[4];
  float* out = (float*)d_out;
  int N = in_sizes[4];  // number of tokens (B*S)

  char* ws = (char*)d_ws;
  int*   hist   = (int*)(ws + 0);
  int*   offs   = (int*)(ws + 512);
  int*   cursor = (int*)(ws + 1024);
  float* Mc     = (float*)(ws + 1536);
  float* S1     = (float*)(ws + 2048);
  int*   sorted = (int*)(ws + 2048 + NCH * DD * 4);

  // zero hist/offs/cursor/Mc/S1 (sorted gets fully overwritten)
  hipMemsetAsync(d_ws, 0, 2048 + NCH * DD * 4, stream);

  int nb = (N + 255) / 256;
  k_hist<<<nb, 256, 0, stream>>>(tgt, N, hist);
  k_scan<<<1, 64, 0, stream>>>(hist, offs);
  k_scatter<<<nb, 256, 0, stream>>>(tgt, N, offs, cursor, sorted);

  // virtual wave space covers the absolute worst case (all tokens one label)
  int virtWaves = NCH * ((N + NTOK - 1) / NTOK);
  k_main<<<2048, 256, 0, stream>>>(x, sorted, offs, hist, S1, Mc, virtWaves);
  k_finish<<<1, 1024, 0, stream>>>(dic, w, b, S1, Mc, hist, out);
}

// Round 2
// 148.800 us; speedup vs baseline: 1.2076x; 1.2076x over previous
//
#include <hip/hip_runtime.h>

#define DD 768
#define NCH 96
#define NTOK 32      // tokens per wave-chunk in main kernel
#define NBLK 128     // blocks for prep/scatter (fixed partition)

// ---- workspace layout (bytes) ----
#define WS_S1      0                         // 96*768*4 = 294912
#define WS_MC      294912                    // 96*4     = 384
#define WS_GS      295296                    // 768*4    = 3072
#define WS_GPOS    298368                    // 4
#define WS_CNT     298372                    // 4
#define WS_ZEND    298376                    // end of zeroed region
#define WS_PHIST   298496                    // 128*96*4 = 49152
#define WS_SORTED  347648                    // N*4

__device__ __forceinline__ float wave_reduce_sum(float v) {
#pragma unroll
  for (int m = 32; m >= 1; m >>= 1) v += __shfl_xor(v, m, 64);
  return v;
}

// ---------- prep: zero accumulators + per-block label histogram (no atomics) ----------
__global__ void __launch_bounds__(256) k_prep(const int* __restrict__ tgt, int n, int chunk,
                                              float* __restrict__ zbase, int* __restrict__ phist) {
  __shared__ int lh[NCH];
  int tid = threadIdx.x, bid = blockIdx.x;
  if (tid < NCH) lh[tid] = 0;
  // zero the accumulator region (74594 floats) cooperatively
  int nz = WS_ZEND / 4;
  for (int i = bid * 256 + tid; i < nz; i += NBLK * 256) zbase[i] = 0.f;
  __syncthreads();
  int beg = bid * chunk, end = min(beg + chunk, n);
  for (int i = beg + tid; i < end; i += 256) atomicAdd(&lh[tgt[i]], 1);
  __syncthreads();
  if (tid < NCH) phist[bid * NCH + tid] = lh[tid];
}

// ---------- scatter: counting sort; each block derives bases from phist (no global atomics) ----------
__global__ void __launch_bounds__(256) k_scatter(const int* __restrict__ tgt, int n, int chunk,
                                                 const int* __restrict__ phist,
                                                 int* __restrict__ sorted) {
  __shared__ int tot[NCH], cbase[NCH], offs_l[NCH], lcnt[NCH];
  int tid = threadIdx.x, bid = blockIdx.x;
  if (tid < NCH) {
    int s = 0, p = 0;
    for (int b = 0; b < NBLK; ++b) {
      int v = phist[b * NCH + tid];
      s += v;
      if (b < bid) p += v;
    }
    tot[tid] = s; cbase[tid] = p; lcnt[tid] = 0;
  }
  __syncthreads();
  if (tid == 0) {
    int off = 0;
    for (int c = 0; c < NCH; ++c) { offs_l[c] = off; off += tot[c]; }
  }
  __syncthreads();
  int beg = bid * chunk, end = min(beg + chunk, n);
  for (int i = beg + tid; i < end; i += 256) {
    int c = tgt[i];
    int r = atomicAdd(&lcnt[c], 1);
    sorted[offs_l[c] + cbase[c] + r] = i;
  }
}

// ---------- main: one read of input_f; balanced chunks; prefetched rows ----------
__global__ void __launch_bounds__(256) k_main(
    const float* __restrict__ x, const int* __restrict__ sorted,
    const int* __restrict__ tgt, int n, int chunks,
    float* __restrict__ S1, float* __restrict__ Mc) {
  int w = (blockIdx.x * blockDim.x + threadIdx.x) >> 6;
  if (w >= chunks) return;
  int lane = threadIdx.x & 63;
  int beg = w * NTOK;
  int cnt = min(NTOK, n - beg);

  // coalesced load of this chunk's token indices + labels, broadcast later via shfl
  int tl = 0, cl = -1;
  if (lane < cnt) { tl = sorted[beg + lane]; cl = tgt[tl]; }

  // prefetch row 0
  int t = __shfl(tl, 0);
  int c = __shfl(cl, 0);
  const float4* r0 = (const float4*)(x + (size_t)t * DD);
  float4 A = r0[lane], B = r0[64 + lane], C = r0[128 + lane];

  float acc[12];
#pragma unroll
  for (int k = 0; k < 12; ++k) acc[k] = 0.f;
  float mcp = 0.f;

  for (int i = 0; i < cnt; ++i) {
    // issue next row's loads before reducing current row
    float4 An, Bn, Cn;
    int cn = -1;
    if (i + 1 < cnt) {
      int tn = __shfl(tl, i + 1);
      cn = __shfl(cl, i + 1);
      const float4* rn = (const float4*)(x + (size_t)tn * DD);
      An = rn[lane]; Bn = rn[64 + lane]; Cn = rn[128 + lane];
    }
    float v[12] = {A.x, A.y, A.z, A.w, B.x, B.y, B.z, B.w, C.x, C.y, C.z, C.w};
    float s = 0.f, q = 0.f;
#pragma unroll
    for (int k = 0; k < 12; ++k) { s += v[k]; q += v[k] * v[k]; }
    s = wave_reduce_sum(s);
    q = wave_reduce_sum(q);
    float mu = s * (1.f / DD);
    float var = q * (1.f / DD) - mu * mu;
    float rstd = rsqrtf(var + 1e-5f);
#pragma unroll
    for (int k = 0; k < 12; ++k) acc[k] += rstd * v[k];
    mcp += rstd * mu;

    if (cn != c) {  // wave-uniform: flush this label's registers (also fires at i==cnt-1)
      float* S1r = S1 + c * DD;
#pragma unroll
      for (int k = 0; k < 12; ++k) {
        int d = (k >> 2) * 256 + 4 * lane + (k & 3);
        atomicAdd(&S1r[d], acc[k]);
      }
      if (lane == 0) atomicAdd(&Mc[c], mcp);
#pragma unroll
      for (int k = 0; k < 12; ++k) acc[k] = 0.f;
      mcp = 0.f;
      c = cn;
    }
    A = An; B = Bn; C = Cn;
  }
}

// ---------- finish: one block per codebook row; last block reduces to scalar ----------
__global__ void __launch_bounds__(64) k_finish(
    const float* __restrict__ dic, const float* __restrict__ wv,
    const float* __restrict__ bv, const float* __restrict__ S1,
    const float* __restrict__ Mc, const int* __restrict__ phist,
    float* __restrict__ gS, float* __restrict__ gpos, int* __restrict__ counter,
    float* __restrict__ out) {
  int c = blockIdx.x, lane = threadIdx.x;

  // total count for this label from per-block histograms
  float s = 0.f;
  for (int b = lane; b < NBLK; b += 64) s += (float)phist[b * NCH + c];
  float nc = wave_reduce_sum(s);

  float mc = Mc[c];
  const float* dr = dic + c * DD;
  const float* sr = S1 + c * DD;

  float g[12];
  float pacc = 0.f;
#pragma unroll
  for (int k = 0; k < 12; ++k) {
    int d = (k >> 2) * 256 + 4 * lane + (k & 3);
    float gg = dr[d] + wv[d] * (sr[d] - mc) + nc * bv[d];
    g[k] = gg;
    pacc += gg * gg;
  }
  pacc = wave_reduce_sum(pacc);
  if (lane == 0) atomicAdd(gpos, pacc);

  if (c >= 1) {
    float inv = 1.f / (nc + 1.f);
    float u[12];
    float sum = 0.f, sq = 0.f;
#pragma unroll
    for (int k = 0; k < 12; ++k) {
      int d = (k >> 2) * 256 + 4 * lane + (k & 3);
      float uu = dr[d] + 0.1f * g[k] * inv;
      u[k] = uu; sum += uu; sq += uu * uu;
    }
    sum = wave_reduce_sum(sum);
    sq = wave_reduce_sum(sq);
    float mu = sum * (1.f / DD);
    float rstd = rsqrtf(sq * (1.f / DD) - mu * mu + 1e-5f);
#pragma unroll
    for (int k = 0; k < 12; ++k) {
      int d = (k >> 2) * 256 + 4 * lane + (k & 3);
      atomicAdd(&gS[d], (u[k] - mu) * rstd * wv[d] + bv[d]);
    }
  }

  __threadfence();
  int done = 0;
  if (lane == 0) done = (atomicAdd(counter, 1) == NCH - 1) ? 1 : 0;
  done = __shfl(done, 0);
  if (done) {
    __threadfence();
    float nv = 0.f;
#pragma unroll
    for (int k = 0; k < 12; ++k) {
      int d = (k >> 2) * 256 + 4 * lane + (k & 3);
      float t = gS[d];
      nv += t * t;
    }
    nv = wave_reduce_sum(nv);
    if (lane == 0) out[0] = (nv - gpos[0]) * (1.f / DD);
  }
}

extern "C" void kernel_launch(void* const* d_in, const int* in_sizes, int n_in,
                              void* d_out, int out_size, void* d_ws, size_t ws_size,
                              hipStream_t stream) {
  (void)n_in; (void)out_size; (void)ws_size;
  const float* x   = (const float*)d_in[0];
  const float* dic = (const float*)d_in[1];
  const float* w   = (const float*)d_in[2];
  const float* b   = (const float*)d_in[3];
  const int*   tgt = (const int*)d_in[4];
  float* out = (float*)d_out;
  int N = in_sizes[4];  // number of tokens (B*S)

  char* ws = (char*)d_ws;
  float* S1     = (float*)(ws + WS_S1);
  float* Mc     = (float*)(ws + WS_MC);
  float* gS     = (float*)(ws + WS_GS);
  float* gpos   = (float*)(ws + WS_GPOS);
  int*   cnt    = (int*)(ws + WS_CNT);
  int*   phist  = (int*)(ws + WS_PHIST);
  int*   sorted = (int*)(ws + WS_SORTED);

  int chunk = (N + NBLK - 1) / NBLK;
  k_prep<<<NBLK, 256, 0, stream>>>(tgt, N, chunk, (float*)ws, phist);
  k_scatter<<<NBLK, 256, 0, stream>>>(tgt, N, chunk, phist, sorted);

  int chunks = (N + NTOK - 1) / NTOK;
  int mblocks = (chunks + 3) / 4;
  k_main<<<mblocks, 256, 0, stream>>>(x, sorted, tgt, N, chunks, S1, Mc);
  k_finish<<<NCH, 64, 0, stream>>>(dic, w, b, S1, Mc, phist, gS, gpos, cnt, out);
}

// Round 3
// 139.451 us; speedup vs baseline: 1.2886x; 1.0670x over previous
//
#include <hip/hip_runtime.h>

#define DD 768
#define NCH 96
#define NTOK 16      // tokens per slot (label-aligned)
#define NBLK 128     // blocks for prep/scatter

__device__ __forceinline__ float wave_reduce_sum(float v) {
#pragma unroll
  for (int m = 32; m >= 1; m >>= 1) v += __shfl_xor(v, m, 64);
  return v;
}

// ---------- prep: zero small accumulators + per-block label histogram ----------
__global__ void __launch_bounds__(256) k_prep(const int* __restrict__ tgt, int n, int chunk,
                                              float* __restrict__ zbase, int* __restrict__ phist) {
  __shared__ int lh[NCH];
  int tid = threadIdx.x, bid = blockIdx.x;
  if (tid < NCH) lh[tid] = 0;
  int gi = bid * 256 + tid;
  if (gi < 800) zbase[gi] = 0.f;   // gS(768) + gpos + counter + pad = 3200 B
  __syncthreads();
  int beg = bid * chunk, end = min(beg + chunk, n);
  for (int i = beg + tid; i < end; i += 256) atomicAdd(&lh[tgt[i]], 1);
  __syncthreads();
  if (tid < NCH) phist[bid * NCH + tid] = lh[tid];
}

// ---------- scatter: counting sort + (block 0) label-aligned slot table ----------
__global__ void __launch_bounds__(256) k_scatter(const int* __restrict__ tgt, int n, int chunk,
                                                 const int* __restrict__ phist,
                                                 int* __restrict__ sorted,
                                                 int* __restrict__ offs_g, int* __restrict__ sbase_g,
                                                 int* __restrict__ nslots,
                                                 int* __restrict__ tbase, int* __restrict__ tcnt) {
  __shared__ int tot[NCH], cbase[NCH], lcnt[NCH];
  __shared__ int offs_l[NCH + 1], sb_l[NCH + 1];
  int tid = threadIdx.x, bid = blockIdx.x;
  if (tid < NCH) {
    int s = 0, p = 0;
    for (int b = 0; b < NBLK; ++b) {
      int v = phist[b * NCH + tid];
      s += v;
      if (b < bid) p += v;
    }
    tot[tid] = s; cbase[tid] = p; lcnt[tid] = 0;
  }
  __syncthreads();
  if (tid == 0) {
    int off = 0, sb = 0;
    for (int c = 0; c < NCH; ++c) {
      offs_l[c] = off; sb_l[c] = sb;
      off += tot[c]; sb += (tot[c] + NTOK - 1) / NTOK;
    }
    offs_l[NCH] = off; sb_l[NCH] = sb;
  }
  __syncthreads();
  if (bid == 0) {
    for (int c = tid; c <= NCH; c += 256) { offs_g[c] = offs_l[c]; sbase_g[c] = sb_l[c]; }
    if (tid == 0) *nslots = sb_l[NCH];
    for (int c = tid; c < NCH; c += 256) {
      int o = offs_l[c], ncnt = tot[c], sb = sb_l[c];
      int nsl = (ncnt + NTOK - 1) / NTOK;
      for (int j = 0; j < nsl; ++j) {
        tbase[sb + j] = o + j * NTOK;
        tcnt[sb + j] = min(NTOK, ncnt - j * NTOK);
      }
    }
  }
  int beg = bid * chunk, end = min(beg + chunk, n);
  for (int i = beg + tid; i < end; i += 256) {
    int c = tgt[i];
    int r = atomicAdd(&lcnt[c], 1);
    sorted[offs_l[c] + cbase[c] + r] = i;
  }
}

// ---------- main: one read of input_f; atomic-free per-slot partial stores ----------
__global__ void __launch_bounds__(256) k_main(
    const float* __restrict__ x, const int* __restrict__ sorted,
    const int* __restrict__ tbase, const int* __restrict__ tcnt,
    const int* __restrict__ nslots,
    float* __restrict__ P, float* __restrict__ Pm) {
  int lane = threadIdx.x & 63;
  int w = (blockIdx.x * blockDim.x + threadIdx.x) >> 6;
  int W = (gridDim.x * blockDim.x) >> 6;
  int S = *nslots;
  for (int s = w; s < S; s += W) {
    int base = tbase[s], cnt = tcnt[s];
    int tl = (lane < cnt) ? sorted[base + lane] : 0;
    int t = __shfl(tl, 0);
    const float4* r0 = (const float4*)(x + (size_t)t * DD);
    float4 A = r0[lane], B = r0[64 + lane], C = r0[128 + lane];
    float acc[12];
#pragma unroll
    for (int k = 0; k < 12; ++k) acc[k] = 0.f;
    float mcp = 0.f;
    for (int i = 0; i < cnt; ++i) {
      float4 An, Bn, Cn;
      if (i + 1 < cnt) {
        int tn = __shfl(tl, i + 1);
        const float4* rn = (const float4*)(x + (size_t)tn * DD);
        An = rn[lane]; Bn = rn[64 + lane]; Cn = rn[128 + lane];
      }
      float v[12] = {A.x, A.y, A.z, A.w, B.x, B.y, B.z, B.w, C.x, C.y, C.z, C.w};
      float ssum = 0.f, q = 0.f;
#pragma unroll
      for (int k = 0; k < 12; ++k) { ssum += v[k]; q += v[k] * v[k]; }
      ssum = wave_reduce_sum(ssum);
      q = wave_reduce_sum(q);
      float mu = ssum * (1.f / DD);
      float var = q * (1.f / DD) - mu * mu;
      float rstd = rsqrtf(var + 1e-5f);
#pragma unroll
      for (int k = 0; k < 12; ++k) acc[k] += rstd * v[k];
      mcp += rstd * mu;
      A = An; B = Bn; C = Cn;
    }
    float4* Pr = (float4*)(P + (size_t)s * DD);
    Pr[lane]       = make_float4(acc[0], acc[1], acc[2], acc[3]);
    Pr[64 + lane]  = make_float4(acc[4], acc[5], acc[6], acc[7]);
    Pr[128 + lane] = make_float4(acc[8], acc[9], acc[10], acc[11]);
    if (lane == 0) Pm[s] = mcp;   // mu/rstd are wave-uniform; lane 0 holds the full sum
  }
}

// ---------- finish: per-label slot reduction + tail math; last block -> scalar ----------
__global__ void __launch_bounds__(256) k_finish(
    const float* __restrict__ dic, const float* __restrict__ wv_,
    const float* __restrict__ bv_, const float* __restrict__ P,
    const float* __restrict__ Pm, const int* __restrict__ offs_g,
    const int* __restrict__ sbase_g,
    float* __restrict__ gS, float* __restrict__ gpos, int* __restrict__ counter,
    float* __restrict__ out) {
  __shared__ float accsh[DD];
  __shared__ float mcsh;
  int c = blockIdx.x, tid = threadIdx.x, lane = tid & 63, wid = tid >> 6;
  for (int i = tid; i < DD; i += 256) accsh[i] = 0.f;
  if (tid == 0) mcsh = 0.f;
  __syncthreads();
  int sb = sbase_g[c], se = sbase_g[c + 1];
  float nc = (float)(offs_g[c + 1] - offs_g[c]);
  float acc[12];
#pragma unroll
  for (int k = 0; k < 12; ++k) acc[k] = 0.f;
  float mcp = 0.f;
  for (int s = sb + wid; s < se; s += 4) {
    const float4* Pr = (const float4*)(P + (size_t)s * DD);
    float4 A = Pr[lane], B = Pr[64 + lane], C = Pr[128 + lane];
    acc[0] += A.x; acc[1] += A.y; acc[2]  += A.z; acc[3]  += A.w;
    acc[4] += B.x; acc[5] += B.y; acc[6]  += B.z; acc[7]  += B.w;
    acc[8] += C.x; acc[9] += C.y; acc[10] += C.z; acc[11] += C.w;
    mcp += Pm[s];
  }
#pragma unroll
  for (int k = 0; k < 12; ++k) {
    int d = (k >> 2) * 256 + 4 * lane + (k & 3);
    atomicAdd(&accsh[d], acc[k]);
  }
  if (lane == 0) atomicAdd(&mcsh, mcp);
  __syncthreads();
  if (wid == 0) {
    float mc = mcsh;
    float g[12], pacc = 0.f;
#pragma unroll
    for (int k = 0; k < 12; ++k) {
      int d = (k >> 2) * 256 + 4 * lane + (k & 3);
      float gg = dic[c * DD + d] + wv_[d] * (accsh[d] - mc) + nc * bv_[d];
      g[k] = gg; pacc += gg * gg;
    }
    pacc = wave_reduce_sum(pacc);
    if (lane == 0) atomicAdd(gpos, pacc);
    if (c >= 1) {
      float inv = 1.f / (nc + 1.f);
      float u[12], sum = 0.f, sq = 0.f;
#pragma unroll
      for (int k = 0; k < 12; ++k) {
        int d = (k >> 2) * 256 + 4 * lane + (k & 3);
        float uu = dic[c * DD + d] + 0.1f * g[k] * inv;
        u[k] = uu; sum += uu; sq += uu * uu;
      }
      sum = wave_reduce_sum(sum);
      sq = wave_reduce_sum(sq);
      float mu = sum * (1.f / DD);
      float rstd = rsqrtf(sq * (1.f / DD) - mu * mu + 1e-5f);
#pragma unroll
      for (int k = 0; k < 12; ++k) {
        int d = (k >> 2) * 256 + 4 * lane + (k & 3);
        atomicAdd(&gS[d], (u[k] - mu) * rstd * wv_[d] + bv_[d]);
      }
    }
    __threadfence();
    int done = 0;
    if (lane == 0) done = (atomicAdd(counter, 1) == NCH - 1) ? 1 : 0;
    done = __shfl(done, 0);
    if (done) {
      __threadfence();
      float nv = 0.f;
#pragma unroll
      for (int k = 0; k < 12; ++k) {
        int d = (k >> 2) * 256 + 4 * lane + (k & 3);
        float t = gS[d];
        nv += t * t;
      }
      nv = wave_reduce_sum(nv);
      if (lane == 0) out[0] = (nv - gpos[0]) * (1.f / DD);
    }
  }
}

extern "C" void kernel_launch(void* const* d_in, const int* in_sizes, int n_in,
                              void* d_out, int out_size, void* d_ws, size_t ws_size,
                              hipStream_t stream) {
  (void)n_in; (void)out_size; (void)ws_size;
  const float* x   = (const float*)d_in[0];
  const float* dic = (const float*)d_in[1];
  const float* w   = (const float*)d_in[2];
  const float* b   = (const float*)d_in[3];
  const int*   tgt = (const int*)d_in[4];
  float* out = (float*)d_out;
  int N = in_sizes[4];  // number of tokens (B*S)

  char* ws = (char*)d_ws;
  float* gS      = (float*)(ws);           // 768*4 = 3072
  float* gpos    = (float*)(ws + 3072);
  int*   counter = (int*)(ws + 3076);
  int*   offs_g  = (int*)(ws + 3200);      // 97*4
  int*   sbase_g = (int*)(ws + 3648);      // 97*4
  int*   nslots  = (int*)(ws + 4096);
  int*   tbase   = (int*)(ws + 4160);

  int maxslots = (N + NTOK - 1) / NTOK + NCH;
  size_t o_tcnt = 4160 + (size_t)maxslots * 4;
  int*   tcnt = (int*)(ws + o_tcnt);
  size_t o_pm = o_tcnt + (size_t)maxslots * 4;
  float* Pm = (float*)(ws + o_pm);
  size_t o_ph = o_pm + (size_t)maxslots * 4;
  int*   phist = (int*)(ws + o_ph);
  size_t o_P = (o_ph + (size_t)NBLK * NCH * 4 + 255) & ~(size_t)255;
  float* P = (float*)(ws + o_P);
  size_t o_sorted = o_P + (size_t)maxslots * DD * 4;
  int*   sorted = (int*)(ws + o_sorted);

  int chunk = (N + NBLK - 1) / NBLK;
  k_prep<<<NBLK, 256, 0, stream>>>(tgt, N, chunk, (float*)ws, phist);
  k_scatter<<<NBLK, 256, 0, stream>>>(tgt, N, chunk, phist, sorted,
                                      offs_g, sbase_g, nslots, tbase, tcnt);
  k_main<<<1024, 256, 0, stream>>>(x, sorted, tbase, tcnt, nslots, P, Pm);
  k_finish<<<NCH, 256, 0, stream>>>(dic, w, b, P, Pm, offs_g, sbase_g,
                                    gS, gpos, counter, out);
}